// Round 6
// baseline (641.161 us; speedup 1.0000x reference)
//
#include <hip/hip_runtime.h>
#include <hip/hip_bf16.h>

#define B_ 8
#define C_ 256
#define S_ 4096
#define G_ 32
#define GC_ 8
#define EPS_ 1e-5f

typedef __attribute__((ext_vector_type(4))) float f32x4;
typedef __attribute__((ext_vector_type(8))) short bf16x8;
typedef __attribute__((ext_vector_type(4))) short bf16x4;
typedef __attribute__((ext_vector_type(4))) unsigned int u32x4;

#define DI __device__ __forceinline__

DI unsigned short f2bf(float f) {
    union { float f; unsigned u; } v; v.f = f;
    unsigned r = v.u + 0x7fffu + ((v.u >> 16) & 1u);
    return (unsigned short)(r >> 16);
}

DI unsigned cvt_pk_bf16(float lo, float hi) {
    unsigned r;
    asm("v_cvt_pk_bf16_f32 %0, %1, %2" : "=v"(r) : "v"(lo), "v"(hi));
    return r;
}

// ---------------- GroupNorm stats: one block per (b, group) ----------------
__global__ __launch_bounds__(256) void k_gn_stats(const float* __restrict__ x,
                                                  float* __restrict__ stats) {
    int bg = blockIdx.x;  // b*32+g ; group channels are contiguous
    const float4* xp = (const float4*)(x + (size_t)bg * (GC_ * S_));
    float s = 0.f, ss = 0.f;
    for (int i = threadIdx.x; i < GC_ * S_ / 4; i += 256) {
        float4 v = xp[i];
        s  += v.x + v.y + v.z + v.w;
        ss += v.x * v.x + v.y * v.y + v.z * v.z + v.w * v.w;
    }
    #pragma unroll
    for (int off = 32; off; off >>= 1) { s += __shfl_down(s, off); ss += __shfl_down(ss, off); }
    __shared__ float rs[4], rss[4];
    int w = threadIdx.x >> 6;
    if ((threadIdx.x & 63) == 0) { rs[w] = s; rss[w] = ss; }
    __syncthreads();
    if (threadIdx.x == 0) {
        float S1 = rs[0] + rs[1] + rs[2] + rs[3];
        float S2 = rss[0] + rss[1] + rss[2] + rss[3];
        float inv = 1.f / (GC_ * S_);
        float mean = S1 * inv;
        float var = S2 * inv - mean * mean;
        stats[bg * 2] = mean;
        stats[bg * 2 + 1] = rsqrtf(var + EPS_);
    }
}

// ------------- GN apply + transpose: x[B][C][S] -> h_sc[B][S][C] bf16 -------------
__global__ __launch_bounds__(256) void k_gn_apply(const float* __restrict__ x,
                                                  const float* __restrict__ stats,
                                                  const float* __restrict__ gw,
                                                  const float* __restrict__ gb,
                                                  unsigned short* __restrict__ h) {
    int b = blockIdx.x >> 6;
    int s0 = (blockIdx.x & 63) * 64;
    __shared__ unsigned short tile[64 * 256];  // [s][c] rows 512B, swizzled
    const float* xb = x + (size_t)b * C_ * S_;
    for (int id = threadIdx.x; id < 256 * 16; id += 256) {
        int c = id >> 4, s4 = id & 15;
        float4 v = *(const float4*)(xb + (size_t)c * S_ + s0 + s4 * 4);
        float mean = stats[(b * G_ + (c >> 3)) * 2];
        float rstd = stats[(b * G_ + (c >> 3)) * 2 + 1];
        float ga = gw[c], be = gb[c];
        float vv[4] = {v.x, v.y, v.z, v.w};
        #pragma unroll
        for (int i = 0; i < 4; i++) {
            int srow = s4 * 4 + i;
            unsigned byte = srow * 512u + c * 2u;
            byte ^= ((srow & 7u) << 4);
            *(unsigned short*)((char*)tile + byte) = f2bf((vv[i] - mean) * rstd * ga + be);
        }
    }
    __syncthreads();
    unsigned short* hb = h + (size_t)b * S_ * C_;
    for (int id = threadIdx.x; id < 2048; id += 256) {
        int srow = id >> 5, ck = id & 31;
        unsigned byte = srow * 512u + ck * 16u;
        byte ^= ((srow & 7u) << 4);
        u32x4 v = *(u32x4*)((char*)tile + byte);
        *(u32x4*)(hb + (size_t)(s0 + srow) * C_ + ck * 8) = v;
    }
}

// ---------------- GEMM: out[m=c_out][n=s] = W[m][k] * Bm[n][k] (+bias ...) ----------------
// MODE 0: Q -> scatter-transposed [S][C] bf16, scaled by qscale
// MODE 1: K -> scatter-transposed [S][C] bf16
// MODE 2: V -> natural [C][S] bf16
// MODE 3: proj -> fp32 natural [C][S] + bias + x residual (final output)
template <int MODE>
__global__ __launch_bounds__(256) void k_gemm(const float* __restrict__ W,
                                              const float* __restrict__ bias,
                                              const unsigned short* __restrict__ Bm,
                                              unsigned short* __restrict__ outb,
                                              float* __restrict__ outf,
                                              const float* __restrict__ xres,
                                              float qscale) {
    // grid: 32 n-tiles x 2 m-tiles x 8 batches = 512 blocks
    int n0 = (blockIdx.x & 31) * 128;
    int m0 = ((blockIdx.x >> 5) & 1) * 128;
    int b = blockIdx.x >> 6;
    __shared__ unsigned short Alds[128 * 64];  // [m][k] rows 128B swizzled
    __shared__ unsigned short Blds[128 * 64];  // [n][k] rows 128B swizzled
    int tid = threadIdx.x;
    int lane = tid & 63, wv = tid >> 6;
    int wm = (wv >> 1) * 64, wn = (wv & 1) * 64;
    int lr = lane & 15, lg = lane >> 4;
    f32x4 acc[4][4] = {};
    const unsigned short* Bb = Bm + (size_t)b * S_ * C_;

    for (int k0 = 0; k0 < 256; k0 += 64) {
        __syncthreads();
        {   // stage A: W rows fp32 -> bf16 ; 128 rows x 64 k
            int row = tid >> 1, half = tid & 1;
            const float* src = W + (size_t)(m0 + row) * C_ + k0 + half * 32;
            unsigned short tmp[32];
            #pragma unroll
            for (int i = 0; i < 8; i++) {
                float4 v = *(const float4*)(src + i * 4);
                tmp[i * 4 + 0] = f2bf(v.x); tmp[i * 4 + 1] = f2bf(v.y);
                tmp[i * 4 + 2] = f2bf(v.z); tmp[i * 4 + 3] = f2bf(v.w);
            }
            #pragma unroll
            for (int i = 0; i < 4; i++) {
                unsigned byte = row * 128u + half * 64u + i * 16u;
                byte ^= ((row & 7u) << 4);
                *(u32x4*)((char*)Alds + byte) = *(u32x4*)(tmp + i * 8);
            }
        }
        #pragma unroll
        for (int i = 0; i < 4; i++) {  // stage B: 128 rows x 64 k bf16 = 1024 16B chunks
            int id = tid + i * 256;
            int row = id >> 3, ck = id & 7;
            u32x4 v = *(const u32x4*)(Bb + (size_t)(n0 + row) * C_ + k0 + ck * 8);
            unsigned byte = row * 128u + ck * 16u;
            byte ^= ((row & 7u) << 4);
            *(u32x4*)((char*)Blds + byte) = v;
        }
        __syncthreads();
        #pragma unroll
        for (int ks = 0; ks < 2; ks++) {
            bf16x8 af[4], bf[4];
            #pragma unroll
            for (int mf = 0; mf < 4; mf++) {
                int m = wm + mf * 16 + lr;
                unsigned byte = m * 128u + ks * 64u + lg * 16u;
                byte ^= ((m & 7u) << 4);
                af[mf] = *(bf16x8*)((char*)Alds + byte);
            }
            #pragma unroll
            for (int nf = 0; nf < 4; nf++) {
                int n = wn + nf * 16 + lr;
                unsigned byte = n * 128u + ks * 64u + lg * 16u;
                byte ^= ((n & 7u) << 4);
                bf[nf] = *(bf16x8*)((char*)Blds + byte);
            }
            #pragma unroll
            for (int mf = 0; mf < 4; mf++)
                #pragma unroll
                for (int nf = 0; nf < 4; nf++)
                    acc[mf][nf] = __builtin_amdgcn_mfma_f32_16x16x32_bf16(af[mf], bf[nf], acc[mf][nf], 0, 0, 0);
        }
    }

    // epilogue: D row m = wm+mf*16+lg*4+r ; col n = wn+nf*16+lr
    if (MODE == 0 || MODE == 1) {
        unsigned short* ob = outb + (size_t)b * S_ * C_;
        #pragma unroll
        for (int mf = 0; mf < 4; mf++)
            #pragma unroll
            for (int nf = 0; nf < 4; nf++) {
                int cbase = m0 + wm + mf * 16 + lg * 4;
                int srow = n0 + wn + nf * 16 + lr;
                bf16x4 pk;
                #pragma unroll
                for (int r = 0; r < 4; r++) {
                    float v = acc[mf][nf][r] + bias[cbase + r];
                    if (MODE == 0) v *= qscale;
                    pk[r] = (short)f2bf(v);
                }
                *(bf16x4*)(ob + (size_t)srow * C_ + cbase) = pk;
            }
    } else if (MODE == 2) {
        unsigned short* ob = outb + (size_t)b * C_ * S_;
        #pragma unroll
        for (int mf = 0; mf < 4; mf++)
            #pragma unroll
            for (int nf = 0; nf < 4; nf++)
                #pragma unroll
                for (int r = 0; r < 4; r++) {
                    int c = m0 + wm + mf * 16 + lg * 4 + r;
                    int s = n0 + wn + nf * 16 + lr;
                    ob[(size_t)c * S_ + s] = f2bf(acc[mf][nf][r] + bias[c]);
                }
    } else {
        float* ob = outf + (size_t)b * C_ * S_;
        const float* xb = xres + (size_t)b * C_ * S_;
        #pragma unroll
        for (int mf = 0; mf < 4; mf++)
            #pragma unroll
            for (int nf = 0; nf < 4; nf++)
                #pragma unroll
                for (int r = 0; r < 4; r++) {
                    int c = m0 + wm + mf * 16 + lg * 4 + r;
                    int s = n0 + wn + nf * 16 + lr;
                    ob[(size_t)c * S_ + s] = acc[mf][nf][r] + bias[c] + xb[(size_t)c * S_ + s];
                }
    }
}

// ---------------- Flash attention v6: dbuf LDS, in-register P, 1 barrier/tile ----------------
// 8 waves: qg = wv&3 (32 queries), kg = wv>>2 (32 keys of each 64-key tile).
// Fixed-offset softmax p = exp2(s-16); scale cancels in O = (sum p*v)/(sum p).
// P stays in registers: cvt_pk_bf16 pack + 16 shfl regroup -> PV B-fragments.
__global__ __launch_bounds__(512, 2) void k_attn(const unsigned short* __restrict__ Q,  // [B][S][C], pre-scaled
                                                 const unsigned short* __restrict__ K,  // [B][S][C]
                                                 const unsigned short* __restrict__ V,  // [B][C][S]
                                                 unsigned short* __restrict__ O) {      // [B][S][C]
    int b = blockIdx.x & 7;           // XCD swizzle: one batch per XCD
    int q0 = (blockIdx.x >> 3) * 128;
    int tid = threadIdx.x, lane = tid & 63, wv = tid >> 6;
    int lr = lane & 15, lg = lane >> 4;
    int qg = wv & 3, kg = wv >> 2;
    int qw = q0 + qg * 32;

    // carve: K2 2x32K | V2 2x32K | mlp 2K ; merge epilogue aliases first 128K
    __shared__ __align__(16) unsigned char SM[133120];
    unsigned char* Kb_ = SM;              // [2][64 key][512B swz]
    unsigned char* Vb_ = SM + 65536;      // [2][256 c][128B swz]
    float* mlp = (float*)(SM + 131072);   // [8 wv][2 qf][16 lr]

    const unsigned short* Qb = Q + (size_t)b * S_ * C_;
    const unsigned short* Kbp = K + (size_t)b * S_ * C_;
    const unsigned short* Vbp = V + (size_t)b * C_ * S_;

    // Q fragments: q = qw + qf*16 + lr, c-chunk = ks*32 + lg*8
    bf16x8 qf_[8][2];
    #pragma unroll
    for (int ks = 0; ks < 8; ks++)
        #pragma unroll
        for (int qf = 0; qf < 2; qf++)
            qf_[ks][qf] = *(const bf16x8*)(Qb + (size_t)(qw + qf * 16 + lr) * C_ + ks * 32 + lg * 8);

    // staging geometry: 2048 16B chunks per K (and V) tile over 512 threads = 4 each
    // chunk i: K row kr0+16i col kck ; V row vc0+64i col vck (swizzle term constant per thread)
    int kck = tid & 31, kr0 = tid >> 5;
    int vck = tid & 7,  vc0 = tid >> 3;
    unsigned kwb = kr0 * 512u + ((unsigned)(kck * 16) ^ ((kr0 & 7u) << 4));
    unsigned vwb = vc0 * 128u + ((unsigned)(vck * 16) ^ ((vc0 & 7u) << 4));

    f32x4 acc[16][2] = {};       // O^T: c = cf*16+lg*4+r, q(local) = qf*16+lr
    float lrun[2] = {0.f, 0.f};  // per-lane partial sum of p

    u32x4 kpre[4], vpre[4];
    // prologue: tile 0 -> regs -> buf0 ; tile 1 -> regs
    #pragma unroll
    for (int i = 0; i < 4; i++) {
        kpre[i] = *(const u32x4*)(Kbp + (size_t)(kr0 + 16 * i) * C_ + kck * 8);
        vpre[i] = *(const u32x4*)(Vbp + (size_t)(vc0 + 64 * i) * S_ + vck * 8);
    }
    #pragma unroll
    for (int i = 0; i < 4; i++) {
        *(u32x4*)(Kb_ + i * 8192u + kwb) = kpre[i];
        *(u32x4*)(Vb_ + i * 8192u + vwb) = vpre[i];
    }
    #pragma unroll
    for (int i = 0; i < 4; i++) {
        kpre[i] = *(const u32x4*)(Kbp + (size_t)(64 + kr0 + 16 * i) * C_ + kck * 8);
        vpre[i] = *(const u32x4*)(Vbp + (size_t)(vc0 + 64 * i) * S_ + 64 + vck * 8);
    }
    __syncthreads();

    for (int kt = 0; kt < 64; kt++) {
        int cur = kt & 1;
        const unsigned char* Kc = Kb_ + cur * 32768;
        const unsigned char* Vc = Vb_ + cur * 32768;

        // publish tile kt+1 (regs -> other buffer); overlaps with compute of cur
        if (kt + 1 < 64) {
            unsigned char* Kn = Kb_ + (cur ^ 1) * 32768;
            unsigned char* Vn = Vb_ + (cur ^ 1) * 32768;
            #pragma unroll
            for (int i = 0; i < 4; i++) {
                *(u32x4*)(Kn + i * 8192u + kwb) = kpre[i];
                *(u32x4*)(Vn + i * 8192u + vwb) = vpre[i];
            }
        }
        // issue tile kt+2 global loads; a full tile of compute to land
        if (kt + 2 < 64) {
            const unsigned short* Ks = Kbp + (size_t)(kt + 2) * 64 * C_;
            const unsigned short* Vs = Vbp + (kt + 2) * 64;
            #pragma unroll
            for (int i = 0; i < 4; i++) {
                kpre[i] = *(const u32x4*)(Ks + (size_t)(kr0 + 16 * i) * C_ + kck * 8);
                vpre[i] = *(const u32x4*)(Vs + (size_t)(vc0 + 64 * i) * S_ + vck * 8);
            }
        }

        // QK^T (swapped): sc[kf][qf] = S[key = kg*32+kf*16+lg*4+r][q = qf*16+lr]
        f32x4 sc[2][2] = {};
        __builtin_amdgcn_s_setprio(1);
        #pragma unroll
        for (int ks = 0; ks < 8; ks++) {
            bf16x8 a[2];
            #pragma unroll
            for (int kf = 0; kf < 2; kf++) {
                int key = kg * 32 + kf * 16 + lr;
                unsigned byte = (unsigned)(key * 512 + ks * 64 + lg * 16) ^ ((key & 7u) << 4);
                a[kf] = *(const bf16x8*)(Kc + byte);
            }
            #pragma unroll
            for (int kf = 0; kf < 2; kf++)
                #pragma unroll
                for (int qf = 0; qf < 2; qf++)
                    sc[kf][qf] = __builtin_amdgcn_mfma_f32_16x16x32_bf16(a[kf], qf_[ks][qf], sc[kf][qf], 0, 0, 0);
        }
        __builtin_amdgcn_s_setprio(0);

        // softmax p = exp2(s-16), pack to bf16 pairs, shfl-regroup into PV B-frags.
        // source: lane (lr,lg) holds keys kf*16+lg*4+r (local); target B-frag needs
        // keys lg*8..lg*8+7: u32[0..1] from lane lg'=2(lg&1), u32[2..3] from lg'+1, kf=lg>>1.
        bf16x8 pb[2];
        int sl0 = lr + ((lg & 1) << 5);  // lane lr + 16*2*(lg&1)
        int sl1 = sl0 + 16;
        #pragma unroll
        for (int qf = 0; qf < 2; qf++) {
            unsigned pk2[2][2];
            float ps = 0.f;
            #pragma unroll
            for (int kf = 0; kf < 2; kf++) {
                float p0 = __builtin_amdgcn_exp2f(sc[kf][qf][0] - 16.f);
                float p1 = __builtin_amdgcn_exp2f(sc[kf][qf][1] - 16.f);
                float p2 = __builtin_amdgcn_exp2f(sc[kf][qf][2] - 16.f);
                float p3 = __builtin_amdgcn_exp2f(sc[kf][qf][3] - 16.f);
                ps += (p0 + p1) + (p2 + p3);
                pk2[kf][0] = cvt_pk_bf16(p0, p1);
                pk2[kf][1] = cvt_pk_bf16(p2, p3);
            }
            lrun[qf] += ps;
            unsigned a00 = __shfl((int)pk2[0][0], sl0), a01 = __shfl((int)pk2[0][1], sl0);
            unsigned a02 = __shfl((int)pk2[0][0], sl1), a03 = __shfl((int)pk2[0][1], sl1);
            unsigned a10 = __shfl((int)pk2[1][0], sl0), a11 = __shfl((int)pk2[1][1], sl0);
            unsigned a12 = __shfl((int)pk2[1][0], sl1), a13 = __shfl((int)pk2[1][1], sl1);
            u32x4 bw;
            bool hi = lg >= 2;
            bw[0] = hi ? a10 : a00; bw[1] = hi ? a11 : a01;
            bw[2] = hi ? a12 : a02; bw[3] = hi ? a13 : a03;
            union { u32x4 u; bf16x8 h; } cvt; cvt.u = bw;
            pb[qf] = cvt.h;
        }

        // PV: O^T[c][q] += V[c][kg keys] * P
        __builtin_amdgcn_s_setprio(1);
        #pragma unroll
        for (int cf = 0; cf < 16; cf++) {
            int c = cf * 16 + lr;
            unsigned byte = (unsigned)(c * 128 + kg * 64 + lg * 16) ^ ((c & 7u) << 4);
            bf16x8 va = *(const bf16x8*)(Vc + byte);
            #pragma unroll
            for (int qf = 0; qf < 2; qf++)
                acc[cf][qf] = __builtin_amdgcn_mfma_f32_16x16x32_bf16(va, pb[qf], acc[cf][qf], 0, 0, 0);
        }
        __builtin_amdgcn_s_setprio(0);

        __syncthreads();  // all waves done reading cur & publishing nxt
    }

    // ---- epilogue: reduce l over lg, exchange across kg, merge acc halves ----
    float ls[2];
    #pragma unroll
    for (int qf = 0; qf < 2; qf++) {
        float t = lrun[qf];
        t += __shfl_xor(t, 16);
        t += __shfl_xor(t, 32);
        ls[qf] = t;
    }
    if (lg == 0) {
        #pragma unroll
        for (int qf = 0; qf < 2; qf++) mlp[(wv * 2 + qf) * 16 + lr] = ls[qf];
    }
    float* mg = (float*)SM;  // reuse K/V region: [128 q][256 c] f32, rows 1024B, swz by ql
    if (kg == 1) {
        #pragma unroll
        for (int qf = 0; qf < 2; qf++) {
            int ql = qf * 16 + lr;
            #pragma unroll
            for (int cf = 0; cf < 16; cf++) {
                unsigned byte = (unsigned)(qg * 32 + ql) * 1024u + (cf * 16u + lg * 4u) * 4u;
                byte ^= ((ql & 7u) << 4);
                *(f32x4*)((char*)mg + byte) = acc[cf][qf];
            }
        }
    }
    __syncthreads();
    if (kg == 0) {
        unsigned short* Ob = O + (size_t)b * S_ * C_;
        #pragma unroll
        for (int qf = 0; qf < 2; qf++) {
            float lpart = mlp[((wv ^ 4) * 2 + qf) * 16 + lr];
            float inv = 1.f / (ls[qf] + lpart);
            int ql = qf * 16 + lr;
            int srow = q0 + qg * 32 + ql;
            #pragma unroll
            for (int cf = 0; cf < 16; cf++) {
                unsigned byte = (unsigned)(qg * 32 + ql) * 1024u + (cf * 16u + lg * 4u) * 4u;
                byte ^= ((ql & 7u) << 4);
                f32x4 pv = *(const f32x4*)((const char*)mg + byte);
                bf16x4 pk;
                #pragma unroll
                for (int r = 0; r < 4; r++)
                    pk[r] = (short)f2bf((acc[cf][qf][r] + pv[r]) * inv);
                *(bf16x4*)(Ob + (size_t)srow * C_ + cf * 16 + lg * 4) = pk;
            }
        }
    }
}

__global__ __launch_bounds__(256) void k_copy_temb(const float* __restrict__ t, float* __restrict__ o) {
    int i = blockIdx.x * 256 + threadIdx.x;
    if (i < B_ * 512) o[i] = t[i];
}

extern "C" void kernel_launch(void* const* d_in, const int* in_sizes, int n_in,
                              void* d_out, int out_size, void* d_ws, size_t ws_size,
                              hipStream_t stream) {
    (void)in_sizes; (void)n_in; (void)out_size; (void)ws_size;
    const float* x  = (const float*)d_in[0];
    const float* temb = (const float*)d_in[1];
    const float* gw = (const float*)d_in[2];
    const float* gb = (const float*)d_in[3];
    const float* wq = (const float*)d_in[4];
    const float* bq = (const float*)d_in[5];
    const float* wk = (const float*)d_in[6];
    const float* bk = (const float*)d_in[7];
    const float* wv = (const float*)d_in[8];
    const float* bv = (const float*)d_in[9];
    const float* wp = (const float*)d_in[10];
    const float* bp = (const float*)d_in[11];
    float* out = (float*)d_out;

    char* ws = (char*)d_ws;
    const size_t MB16 = (size_t)B_ * S_ * C_ * 2;           // 16 MB
    unsigned short* h_sc = (unsigned short*)ws;             // [B][S][C]; reused for attn out
    unsigned short* q_sc = (unsigned short*)(ws + MB16);    // [B][S][C]
    unsigned short* k_sc = (unsigned short*)(ws + 2 * MB16);// [B][S][C]
    unsigned short* v_cs = (unsigned short*)(ws + 3 * MB16);// [B][C][S]
    float* stats = (float*)(ws + 4 * MB16);                 // [B*G][2]

    const float qscale = 0.0625f * 1.4426950408889634f;  // C^-0.5 * log2(e)

    k_gn_stats<<<B_ * G_, 256, 0, stream>>>(x, stats);
    k_gn_apply<<<B_ * (S_ / 64), 256, 0, stream>>>(x, stats, gw, gb, h_sc);
    k_gemm<0><<<512, 256, 0, stream>>>(wq, bq, h_sc, q_sc, nullptr, nullptr, qscale);
    k_gemm<1><<<512, 256, 0, stream>>>(wk, bk, h_sc, k_sc, nullptr, nullptr, 1.f);
    k_gemm<2><<<512, 256, 0, stream>>>(wv, bv, h_sc, v_cs, nullptr, nullptr, 1.f);
    k_attn<<<B_ * (S_ / 128), 512, 0, stream>>>(q_sc, k_sc, v_cs, h_sc);
    k_gemm<3><<<512, 256, 0, stream>>>(wp, bp, h_sc, nullptr, out, x, 1.f);
    k_copy_temb<<<(B_ * 512 + 255) / 256, 256, 0, stream>>>(temb, out + (size_t)B_ * C_ * S_);
}

// Round 7
// 621.562 us; speedup vs baseline: 1.0315x; 1.0315x over previous
//
#include <hip/hip_runtime.h>
#include <hip/hip_bf16.h>

#define B_ 8
#define C_ 256
#define S_ 4096
#define G_ 32
#define GC_ 8
#define EPS_ 1e-5f

typedef __attribute__((ext_vector_type(4))) float f32x4;
typedef __attribute__((ext_vector_type(8))) short bf16x8;
typedef __attribute__((ext_vector_type(4))) short bf16x4;
typedef __attribute__((ext_vector_type(4))) unsigned int u32x4;

#define DI __device__ __forceinline__

DI unsigned short f2bf(float f) {
    union { float f; unsigned u; } v; v.f = f;
    unsigned r = v.u + 0x7fffu + ((v.u >> 16) & 1u);
    return (unsigned short)(r >> 16);
}

// ---------------- GroupNorm stats: one block per (b, group) ----------------
__global__ __launch_bounds__(256) void k_gn_stats(const float* __restrict__ x,
                                                  float* __restrict__ stats) {
    int bg = blockIdx.x;  // b*32+g ; group channels are contiguous
    const float4* xp = (const float4*)(x + (size_t)bg * (GC_ * S_));
    float s = 0.f, ss = 0.f;
    for (int i = threadIdx.x; i < GC_ * S_ / 4; i += 256) {
        float4 v = xp[i];
        s  += v.x + v.y + v.z + v.w;
        ss += v.x * v.x + v.y * v.y + v.z * v.z + v.w * v.w;
    }
    #pragma unroll
    for (int off = 32; off; off >>= 1) { s += __shfl_down(s, off); ss += __shfl_down(ss, off); }
    __shared__ float rs[4], rss[4];
    int w = threadIdx.x >> 6;
    if ((threadIdx.x & 63) == 0) { rs[w] = s; rss[w] = ss; }
    __syncthreads();
    if (threadIdx.x == 0) {
        float S1 = rs[0] + rs[1] + rs[2] + rs[3];
        float S2 = rss[0] + rss[1] + rss[2] + rss[3];
        float inv = 1.f / (GC_ * S_);
        float mean = S1 * inv;
        float var = S2 * inv - mean * mean;
        stats[bg * 2] = mean;
        stats[bg * 2 + 1] = rsqrtf(var + EPS_);
    }
}

// ------------- GN apply + transpose: x[B][C][S] -> h_sc[B][S][C] bf16 -------------
__global__ __launch_bounds__(256) void k_gn_apply(const float* __restrict__ x,
                                                  const float* __restrict__ stats,
                                                  const float* __restrict__ gw,
                                                  const float* __restrict__ gb,
                                                  unsigned short* __restrict__ h) {
    int b = blockIdx.x >> 6;
    int s0 = (blockIdx.x & 63) * 64;
    __shared__ unsigned short tile[64 * 256];  // [s][c] rows 512B, swizzled
    const float* xb = x + (size_t)b * C_ * S_;
    for (int id = threadIdx.x; id < 256 * 16; id += 256) {
        int c = id >> 4, s4 = id & 15;
        float4 v = *(const float4*)(xb + (size_t)c * S_ + s0 + s4 * 4);
        float mean = stats[(b * G_ + (c >> 3)) * 2];
        float rstd = stats[(b * G_ + (c >> 3)) * 2 + 1];
        float ga = gw[c], be = gb[c];
        float vv[4] = {v.x, v.y, v.z, v.w};
        #pragma unroll
        for (int i = 0; i < 4; i++) {
            int srow = s4 * 4 + i;
            unsigned byte = srow * 512u + c * 2u;
            byte ^= ((srow & 7u) << 4);
            *(unsigned short*)((char*)tile + byte) = f2bf((vv[i] - mean) * rstd * ga + be);
        }
    }
    __syncthreads();
    unsigned short* hb = h + (size_t)b * S_ * C_;
    for (int id = threadIdx.x; id < 2048; id += 256) {
        int srow = id >> 5, ck = id & 31;
        unsigned byte = srow * 512u + ck * 16u;
        byte ^= ((srow & 7u) << 4);
        u32x4 v = *(u32x4*)((char*)tile + byte);
        *(u32x4*)(hb + (size_t)(s0 + srow) * C_ + ck * 8) = v;
    }
}

// ---------------- GEMM: out[m=c_out][n=s] = W[m][k] * Bm[n][k] (+bias ...) ----------------
// MODE 0: Q -> scatter-transposed [S][C] bf16, scaled by qscale
// MODE 1: K -> scatter-transposed [S][C] bf16
// MODE 2: V -> natural [C][S] bf16
// MODE 3: proj -> fp32 natural [C][S] + bias + x residual (final output)
template <int MODE>
__global__ __launch_bounds__(256) void k_gemm(const float* __restrict__ W,
                                              const float* __restrict__ bias,
                                              const unsigned short* __restrict__ Bm,
                                              unsigned short* __restrict__ outb,
                                              float* __restrict__ outf,
                                              const float* __restrict__ xres,
                                              float qscale) {
    // grid: 32 n-tiles x 2 m-tiles x 8 batches = 512 blocks
    int n0 = (blockIdx.x & 31) * 128;
    int m0 = ((blockIdx.x >> 5) & 1) * 128;
    int b = blockIdx.x >> 6;
    __shared__ unsigned short Alds[128 * 64];  // [m][k] rows 128B swizzled
    __shared__ unsigned short Blds[128 * 64];  // [n][k] rows 128B swizzled
    int tid = threadIdx.x;
    int lane = tid & 63, wv = tid >> 6;
    int wm = (wv >> 1) * 64, wn = (wv & 1) * 64;
    int lr = lane & 15, lg = lane >> 4;
    f32x4 acc[4][4] = {};
    const unsigned short* Bb = Bm + (size_t)b * S_ * C_;

    for (int k0 = 0; k0 < 256; k0 += 64) {
        __syncthreads();
        {   // stage A: W rows fp32 -> bf16 ; 128 rows x 64 k
            int row = tid >> 1, half = tid & 1;
            const float* src = W + (size_t)(m0 + row) * C_ + k0 + half * 32;
            unsigned short tmp[32];
            #pragma unroll
            for (int i = 0; i < 8; i++) {
                float4 v = *(const float4*)(src + i * 4);
                tmp[i * 4 + 0] = f2bf(v.x); tmp[i * 4 + 1] = f2bf(v.y);
                tmp[i * 4 + 2] = f2bf(v.z); tmp[i * 4 + 3] = f2bf(v.w);
            }
            #pragma unroll
            for (int i = 0; i < 4; i++) {
                unsigned byte = row * 128u + half * 64u + i * 16u;
                byte ^= ((row & 7u) << 4);
                *(u32x4*)((char*)Alds + byte) = *(u32x4*)(tmp + i * 8);
            }
        }
        #pragma unroll
        for (int i = 0; i < 4; i++) {  // stage B: 128 rows x 64 k bf16 = 1024 16B chunks
            int id = tid + i * 256;
            int row = id >> 3, ck = id & 7;
            u32x4 v = *(const u32x4*)(Bb + (size_t)(n0 + row) * C_ + k0 + ck * 8);
            unsigned byte = row * 128u + ck * 16u;
            byte ^= ((row & 7u) << 4);
            *(u32x4*)((char*)Blds + byte) = v;
        }
        __syncthreads();
        #pragma unroll
        for (int ks = 0; ks < 2; ks++) {
            bf16x8 af[4], bf[4];
            #pragma unroll
            for (int mf = 0; mf < 4; mf++) {
                int m = wm + mf * 16 + lr;
                unsigned byte = m * 128u + ks * 64u + lg * 16u;
                byte ^= ((m & 7u) << 4);
                af[mf] = *(bf16x8*)((char*)Alds + byte);
            }
            #pragma unroll
            for (int nf = 0; nf < 4; nf++) {
                int n = wn + nf * 16 + lr;
                unsigned byte = n * 128u + ks * 64u + lg * 16u;
                byte ^= ((n & 7u) << 4);
                bf[nf] = *(bf16x8*)((char*)Blds + byte);
            }
            #pragma unroll
            for (int mf = 0; mf < 4; mf++)
                #pragma unroll
                for (int nf = 0; nf < 4; nf++)
                    acc[mf][nf] = __builtin_amdgcn_mfma_f32_16x16x32_bf16(af[mf], bf[nf], acc[mf][nf], 0, 0, 0);
        }
    }

    // epilogue: D row m = wm+mf*16+lg*4+r ; col n = wn+nf*16+lr
    if (MODE == 0 || MODE == 1) {
        unsigned short* ob = outb + (size_t)b * S_ * C_;
        #pragma unroll
        for (int mf = 0; mf < 4; mf++)
            #pragma unroll
            for (int nf = 0; nf < 4; nf++) {
                int cbase = m0 + wm + mf * 16 + lg * 4;
                int srow = n0 + wn + nf * 16 + lr;
                bf16x4 pk;
                #pragma unroll
                for (int r = 0; r < 4; r++) {
                    float v = acc[mf][nf][r] + bias[cbase + r];
                    if (MODE == 0) v *= qscale;
                    pk[r] = (short)f2bf(v);
                }
                *(bf16x4*)(ob + (size_t)srow * C_ + cbase) = pk;
            }
    } else if (MODE == 2) {
        unsigned short* ob = outb + (size_t)b * C_ * S_;
        #pragma unroll
        for (int mf = 0; mf < 4; mf++)
            #pragma unroll
            for (int nf = 0; nf < 4; nf++)
                #pragma unroll
                for (int r = 0; r < 4; r++) {
                    int c = m0 + wm + mf * 16 + lg * 4 + r;
                    int s = n0 + wn + nf * 16 + lr;
                    ob[(size_t)c * S_ + s] = f2bf(acc[mf][nf][r] + bias[c]);
                }
    } else {
        float* ob = outf + (size_t)b * C_ * S_;
        const float* xb = xres + (size_t)b * C_ * S_;
        #pragma unroll
        for (int mf = 0; mf < 4; mf++)
            #pragma unroll
            for (int nf = 0; nf < 4; nf++)
                #pragma unroll
                for (int r = 0; r < 4; r++) {
                    int c = m0 + wm + mf * 16 + lg * 4 + r;
                    int s = n0 + wn + nf * 16 + lr;
                    ob[(size_t)c * S_ + s] = acc[mf][nf][r] + bias[c] + xb[(size_t)c * S_ + s];
                }
    }
}

// ---------------- Flash attention v7: 64q blocks, 2 blocks/CU, (qg,kg) split ----------------
// 4 waves: qg = wv&1 (32 queries each), kg = wv>>1 (32 keys of each 64-key tile).
// Each K/V LDS fragment feeds 2 MFMAs. Fixed-offset softmax p = exp2(s-16):
// scale cancels in O = (sum p*v)/(sum p). Reg-staged prefetch, 2 barriers/tile.
// LDS 74.5 KB -> 2 independent blocks/CU (cross-block phase overlap).
__global__ __launch_bounds__(256, 2) void k_attn(const unsigned short* __restrict__ Q,  // [B][S][C], pre-scaled
                                                 const unsigned short* __restrict__ K,  // [B][S][C]
                                                 const unsigned short* __restrict__ V,  // [B][C][S]
                                                 unsigned short* __restrict__ O) {      // [B][S][C]
    int b = blockIdx.x & 7;            // XCD swizzle: one batch per XCD (64 blocks -> 32 CUs)
    int q0 = (blockIdx.x >> 3) * 64;
    int tid = threadIdx.x, lane = tid & 63, wv = tid >> 6;  // 4 waves
    int lr = lane & 15, lg = lane >> 4;
    int qg = wv & 1, kg = wv >> 1;
    int qw = q0 + qg * 32;

    // carve: Klds 32K | Vlds 32K | P 4x2560 | mlp 512B = 76288 B total
    __shared__ __align__(16) unsigned char SM[76288];
    unsigned char* Klds = SM;                      // [64 key][512B] swz
    unsigned char* Vlds = SM + 32768;              // [256 c][128B] swz
    unsigned char* Pw   = SM + 65536 + wv * 2560;  // wave-private [32 q][80B]
    float* mlp = (float*)(SM + 75776);             // [4 wv][2 qf][16 lr]

    const unsigned short* Qb = Q + (size_t)b * S_ * C_;
    const unsigned short* Kbp = K + (size_t)b * S_ * C_;
    const unsigned short* Vbp = V + (size_t)b * C_ * S_;

    // Q fragments: q = qw + qf*16 + lr, c-chunk = ks*32 + lg*8
    bf16x8 qf_[8][2];
    #pragma unroll
    for (int ks = 0; ks < 8; ks++)
        #pragma unroll
        for (int qf = 0; qf < 2; qf++)
            qf_[ks][qf] = *(const bf16x8*)(Qb + (size_t)(qw + qf * 16 + lr) * C_ + ks * 32 + lg * 8);

    // staging: 2048 16B chunks per K (and V) tile over 256 threads = 8 each.
    // K chunk i: row kr0+8i (kr0 = tid>>5 in 0..7), col kck = tid&31  -> row&7 const
    // V chunk i: row vc0+32i (vc0 = tid>>3 in 0..31), col vck = tid&7 -> row&7 const
    int kck = tid & 31, kr0 = tid >> 5;
    int vck = tid & 7,  vc0 = tid >> 3;
    unsigned kwb = kr0 * 512u + ((unsigned)(kck * 16) ^ ((kr0 & 7u) << 4));
    unsigned vwb = vc0 * 128u + ((unsigned)(vck * 16) ^ ((vc0 & 7u) << 4));

    f32x4 acc[16][2] = {};       // O^T: c = cf*16+lg*4+r, q(local) = qf*16+lr
    float lrun[2] = {0.f, 0.f};  // per-lane partial sum of p

    u32x4 kpre[8], vpre[8];
    // prologue: load tile 0 into regs
    #pragma unroll
    for (int i = 0; i < 8; i++) {
        kpre[i] = *(const u32x4*)(Kbp + (size_t)(kr0 + 8 * i) * C_ + kck * 8);
        vpre[i] = *(const u32x4*)(Vbp + (size_t)(vc0 + 32 * i) * S_ + vck * 8);
    }

    for (int kt = 0; kt < 64; kt++) {
        // publish staged tile (regs -> LDS, XOR-swizzled)
        #pragma unroll
        for (int i = 0; i < 8; i++) {
            *(u32x4*)(Klds + kwb + 4096u * i) = kpre[i];
            *(u32x4*)(Vlds + vwb + 4096u * i) = vpre[i];
        }
        __syncthreads();

        bool pf = (kt + 1) < 64;
        if (pf) {  // K prefetch now; V prefetch after softmax (stagger VGPR peak)
            const unsigned short* Ks = Kbp + (size_t)(kt + 1) * 64 * C_;
            #pragma unroll
            for (int i = 0; i < 8; i++)
                kpre[i] = *(const u32x4*)(Ks + (size_t)(kr0 + 8 * i) * C_ + kck * 8);
        }

        // QK^T (swapped): sc[kf][qf] = S[key = kg*32+kf*16+lg*4+r][q = qf*16+lr]
        f32x4 sc[2][2] = {};
        #pragma unroll
        for (int ks = 0; ks < 8; ks++) {
            bf16x8 a[2];
            #pragma unroll
            for (int kf = 0; kf < 2; kf++) {
                int key = kg * 32 + kf * 16 + lr;
                unsigned byte = (unsigned)(key * 512 + ks * 64 + lg * 16) ^ ((key & 7u) << 4);
                a[kf] = *(const bf16x8*)(Klds + byte);
            }
            #pragma unroll
            for (int kf = 0; kf < 2; kf++)
                #pragma unroll
                for (int qf = 0; qf < 2; qf++)
                    sc[kf][qf] = __builtin_amdgcn_mfma_f32_16x16x32_bf16(a[kf], qf_[ks][qf], sc[kf][qf], 0, 0, 0);
        }

        // fixed-offset softmax: p = exp2(s - 16); scale cancels at the end
        #pragma unroll
        for (int qf = 0; qf < 2; qf++)
            #pragma unroll
            for (int kf = 0; kf < 2; kf++) {
                bf16x4 pk;
                #pragma unroll
                for (int r = 0; r < 4; r++) {
                    float p = __builtin_amdgcn_exp2f(sc[kf][qf][r] - 16.f);
                    lrun[qf] += p;
                    pk[r] = (short)f2bf(p);
                }
                *(bf16x4*)(Pw + (unsigned)(qf * 16 + lr) * 80u + kf * 32u + lg * 8u) = pk;
            }

        if (pf) {
            const unsigned short* Vs = Vbp + (kt + 1) * 64;
            #pragma unroll
            for (int i = 0; i < 8; i++)
                vpre[i] = *(const u32x4*)(Vs + (size_t)(vc0 + 32 * i) * S_ + vck * 8);
        }

        // PV: O^T[c][q] += V[c][kg keys] * P
        bf16x8 pb[2];
        #pragma unroll
        for (int qf = 0; qf < 2; qf++)
            pb[qf] = *(const bf16x8*)(Pw + (unsigned)(qf * 16 + lr) * 80u + lg * 16u);
        #pragma unroll
        for (int cf = 0; cf < 16; cf++) {
            int c = cf * 16 + lr;
            unsigned byte = (unsigned)(c * 128 + kg * 64 + lg * 16) ^ ((c & 7u) << 4);
            bf16x8 va = *(const bf16x8*)(Vlds + byte);
            #pragma unroll
            for (int qf = 0; qf < 2; qf++)
                acc[cf][qf] = __builtin_amdgcn_mfma_f32_16x16x32_bf16(va, pb[qf], acc[cf][qf], 0, 0, 0);
        }

        __syncthreads();  // all waves done reading Klds/Vlds; next publish is safe
    }

    // ---- epilogue: reduce l over lg, exchange across kg, merge acc halves ----
    float ls[2];
    #pragma unroll
    for (int qf = 0; qf < 2; qf++) {
        float t = lrun[qf];
        t += __shfl_xor(t, 16);
        t += __shfl_xor(t, 32);
        ls[qf] = t;
    }
    if (lg == 0) {
        #pragma unroll
        for (int qf = 0; qf < 2; qf++) mlp[(wv * 2 + qf) * 16 + lr] = ls[qf];
    }
    float* mg = (float*)SM;  // reuse K/V region: [64 q][256 c] f32, rows 1024B, swz by ql
    if (kg == 1) {
        #pragma unroll
        for (int qf = 0; qf < 2; qf++) {
            int ql = qg * 32 + qf * 16 + lr;
            #pragma unroll
            for (int cf = 0; cf < 16; cf++) {
                unsigned byte = (unsigned)ql * 1024u + (cf * 16u + lg * 4u) * 4u;
                byte ^= ((ql & 7u) << 4);
                *(f32x4*)((char*)mg + byte) = acc[cf][qf];
            }
        }
    }
    __syncthreads();
    if (kg == 0) {
        unsigned short* Ob = O + (size_t)b * S_ * C_;
        #pragma unroll
        for (int qf = 0; qf < 2; qf++) {
            float lpart = mlp[((wv ^ 2) * 2 + qf) * 16 + lr];
            float inv = 1.f / (ls[qf] + lpart);
            int ql = qg * 32 + qf * 16 + lr;
            int srow = q0 + ql;
            #pragma unroll
            for (int cf = 0; cf < 16; cf++) {
                unsigned byte = (unsigned)ql * 1024u + (cf * 16u + lg * 4u) * 4u;
                byte ^= ((ql & 7u) << 4);
                f32x4 pv = *(const f32x4*)((const char*)mg + byte);
                bf16x4 pk;
                #pragma unroll
                for (int r = 0; r < 4; r++)
                    pk[r] = (short)f2bf((acc[cf][qf][r] + pv[r]) * inv);
                *(bf16x4*)(Ob + (size_t)srow * C_ + cf * 16 + lg * 4) = pk;
            }
        }
    }
}

__global__ __launch_bounds__(256) void k_copy_temb(const float* __restrict__ t, float* __restrict__ o) {
    int i = blockIdx.x * 256 + threadIdx.x;
    if (i < B_ * 512) o[i] = t[i];
}

extern "C" void kernel_launch(void* const* d_in, const int* in_sizes, int n_in,
                              void* d_out, int out_size, void* d_ws, size_t ws_size,
                              hipStream_t stream) {
    (void)in_sizes; (void)n_in; (void)out_size; (void)ws_size;
    const float* x  = (const float*)d_in[0];
    const float* temb = (const float*)d_in[1];
    const float* gw = (const float*)d_in[2];
    const float* gb = (const float*)d_in[3];
    const float* wq = (const float*)d_in[4];
    const float* bq = (const float*)d_in[5];
    const float* wk = (const float*)d_in[6];
    const float* bk = (const float*)d_in[7];
    const float* wv = (const float*)d_in[8];
    const float* bv = (const float*)d_in[9];
    const float* wp = (const float*)d_in[10];
    const float* bp = (const float*)d_in[11];
    float* out = (float*)d_out;

    char* ws = (char*)d_ws;
    const size_t MB16 = (size_t)B_ * S_ * C_ * 2;           // 16 MB
    unsigned short* h_sc = (unsigned short*)ws;             // [B][S][C]; reused for attn out
    unsigned short* q_sc = (unsigned short*)(ws + MB16);    // [B][S][C]
    unsigned short* k_sc = (unsigned short*)(ws + 2 * MB16);// [B][S][C]
    unsigned short* v_cs = (unsigned short*)(ws + 3 * MB16);// [B][C][S]
    float* stats = (float*)(ws + 4 * MB16);                 // [B*G][2]

    const float qscale = 0.0625f * 1.4426950408889634f;  // C^-0.5 * log2(e)

    k_gn_stats<<<B_ * G_, 256, 0, stream>>>(x, stats);
    k_gn_apply<<<B_ * (S_ / 64), 256, 0, stream>>>(x, stats, gw, gb, h_sc);
    k_gemm<0><<<512, 256, 0, stream>>>(wq, bq, h_sc, q_sc, nullptr, nullptr, qscale);
    k_gemm<1><<<512, 256, 0, stream>>>(wk, bk, h_sc, k_sc, nullptr, nullptr, 1.f);
    k_gemm<2><<<512, 256, 0, stream>>>(wv, bv, h_sc, v_cs, nullptr, nullptr, 1.f);
    k_attn<<<B_ * (S_ / 64), 256, 0, stream>>>(q_sc, k_sc, v_cs, h_sc);
    k_gemm<3><<<512, 256, 0, stream>>>(wp, bp, h_sc, nullptr, out, x, 1.f);
    k_copy_temb<<<(B_ * 512 + 255) / 256, 256, 0, stream>>>(temb, out + (size_t)B_ * C_ * S_);
}

// Round 8
// 257.925 us; speedup vs baseline: 2.4858x; 2.4099x over previous
//
#include <hip/hip_runtime.h>
#include <hip/hip_bf16.h>

#define B_ 8
#define C_ 256
#define S_ 4096
#define G_ 32
#define GC_ 8
#define EPS_ 1e-5f

typedef __attribute__((ext_vector_type(4))) float f32x4;
typedef __attribute__((ext_vector_type(8))) short bf16x8;
typedef __attribute__((ext_vector_type(4))) short bf16x4;
typedef __attribute__((ext_vector_type(4))) unsigned int u32x4;

#define DI __device__ __forceinline__

DI unsigned short f2bf(float f) {
    union { float f; unsigned u; } v; v.f = f;
    unsigned r = v.u + 0x7fffu + ((v.u >> 16) & 1u);
    return (unsigned short)(r >> 16);
}

// ---------------- GroupNorm stats: one block per (b, group) ----------------
__global__ __launch_bounds__(256) void k_gn_stats(const float* __restrict__ x,
                                                  float* __restrict__ stats) {
    int bg = blockIdx.x;  // b*32+g ; group channels are contiguous
    const float4* xp = (const float4*)(x + (size_t)bg * (GC_ * S_));
    float s = 0.f, ss = 0.f;
    for (int i = threadIdx.x; i < GC_ * S_ / 4; i += 256) {
        float4 v = xp[i];
        s  += v.x + v.y + v.z + v.w;
        ss += v.x * v.x + v.y * v.y + v.z * v.z + v.w * v.w;
    }
    #pragma unroll
    for (int off = 32; off; off >>= 1) { s += __shfl_down(s, off); ss += __shfl_down(ss, off); }
    __shared__ float rs[4], rss[4];
    int w = threadIdx.x >> 6;
    if ((threadIdx.x & 63) == 0) { rs[w] = s; rss[w] = ss; }
    __syncthreads();
    if (threadIdx.x == 0) {
        float S1 = rs[0] + rs[1] + rs[2] + rs[3];
        float S2 = rss[0] + rss[1] + rss[2] + rss[3];
        float inv = 1.f / (GC_ * S_);
        float mean = S1 * inv;
        float var = S2 * inv - mean * mean;
        stats[bg * 2] = mean;
        stats[bg * 2 + 1] = rsqrtf(var + EPS_);
    }
}

// ------------- GN apply + transpose: x[B][C][S] -> h_sc[B][S][C] bf16 -------------
__global__ __launch_bounds__(256) void k_gn_apply(const float* __restrict__ x,
                                                  const float* __restrict__ stats,
                                                  const float* __restrict__ gw,
                                                  const float* __restrict__ gb,
                                                  unsigned short* __restrict__ h) {
    int b = blockIdx.x >> 6;
    int s0 = (blockIdx.x & 63) * 64;
    __shared__ unsigned short tile[64 * 256];  // [s][c] rows 512B, swizzled
    const float* xb = x + (size_t)b * C_ * S_;
    for (int id = threadIdx.x; id < 256 * 16; id += 256) {
        int c = id >> 4, s4 = id & 15;
        float4 v = *(const float4*)(xb + (size_t)c * S_ + s0 + s4 * 4);
        float mean = stats[(b * G_ + (c >> 3)) * 2];
        float rstd = stats[(b * G_ + (c >> 3)) * 2 + 1];
        float ga = gw[c], be = gb[c];
        float vv[4] = {v.x, v.y, v.z, v.w};
        #pragma unroll
        for (int i = 0; i < 4; i++) {
            int srow = s4 * 4 + i;
            unsigned byte = srow * 512u + c * 2u;
            byte ^= ((srow & 7u) << 4);
            *(unsigned short*)((char*)tile + byte) = f2bf((vv[i] - mean) * rstd * ga + be);
        }
    }
    __syncthreads();
    unsigned short* hb = h + (size_t)b * S_ * C_;
    for (int id = threadIdx.x; id < 2048; id += 256) {
        int srow = id >> 5, ck = id & 31;
        unsigned byte = srow * 512u + ck * 16u;
        byte ^= ((srow & 7u) << 4);
        u32x4 v = *(u32x4*)((char*)tile + byte);
        *(u32x4*)(hb + (size_t)(s0 + srow) * C_ + ck * 8) = v;
    }
}

// ---------------- GEMM: out[m=c_out][n=s] = W[m][k] * Bm[n][k] (+bias ...) ----------------
// MODE 0: Q -> scatter-transposed [S][C] bf16, scaled by qscale
// MODE 1: K -> scatter-transposed [S][C] bf16
// MODE 2: V -> natural [C][S] bf16
// MODE 3: proj -> fp32 natural [C][S] + bias + x residual (final output)
template <int MODE>
__global__ __launch_bounds__(256) void k_gemm(const float* __restrict__ W,
                                              const float* __restrict__ bias,
                                              const unsigned short* __restrict__ Bm,
                                              unsigned short* __restrict__ outb,
                                              float* __restrict__ outf,
                                              const float* __restrict__ xres,
                                              float qscale) {
    // grid: 32 n-tiles x 2 m-tiles x 8 batches = 512 blocks
    int n0 = (blockIdx.x & 31) * 128;
    int m0 = ((blockIdx.x >> 5) & 1) * 128;
    int b = blockIdx.x >> 6;
    __shared__ unsigned short Alds[128 * 64];  // [m][k] rows 128B swizzled
    __shared__ unsigned short Blds[128 * 64];  // [n][k] rows 128B swizzled
    int tid = threadIdx.x;
    int lane = tid & 63, wv = tid >> 6;
    int wm = (wv >> 1) * 64, wn = (wv & 1) * 64;
    int lr = lane & 15, lg = lane >> 4;
    f32x4 acc[4][4] = {};
    const unsigned short* Bb = Bm + (size_t)b * S_ * C_;

    for (int k0 = 0; k0 < 256; k0 += 64) {
        __syncthreads();
        {   // stage A: W rows fp32 -> bf16 ; 128 rows x 64 k
            int row = tid >> 1, half = tid & 1;
            const float* src = W + (size_t)(m0 + row) * C_ + k0 + half * 32;
            unsigned short tmp[32];
            #pragma unroll
            for (int i = 0; i < 8; i++) {
                float4 v = *(const float4*)(src + i * 4);
                tmp[i * 4 + 0] = f2bf(v.x); tmp[i * 4 + 1] = f2bf(v.y);
                tmp[i * 4 + 2] = f2bf(v.z); tmp[i * 4 + 3] = f2bf(v.w);
            }
            #pragma unroll
            for (int i = 0; i < 4; i++) {
                unsigned byte = row * 128u + half * 64u + i * 16u;
                byte ^= ((row & 7u) << 4);
                *(u32x4*)((char*)Alds + byte) = *(u32x4*)(tmp + i * 8);
            }
        }
        #pragma unroll
        for (int i = 0; i < 4; i++) {  // stage B: 128 rows x 64 k bf16 = 1024 16B chunks
            int id = tid + i * 256;
            int row = id >> 3, ck = id & 7;
            u32x4 v = *(const u32x4*)(Bb + (size_t)(n0 + row) * C_ + k0 + ck * 8);
            unsigned byte = row * 128u + ck * 16u;
            byte ^= ((row & 7u) << 4);
            *(u32x4*)((char*)Blds + byte) = v;
        }
        __syncthreads();
        #pragma unroll
        for (int ks = 0; ks < 2; ks++) {
            bf16x8 af[4], bf[4];
            #pragma unroll
            for (int mf = 0; mf < 4; mf++) {
                int m = wm + mf * 16 + lr;
                unsigned byte = m * 128u + ks * 64u + lg * 16u;
                byte ^= ((m & 7u) << 4);
                af[mf] = *(bf16x8*)((char*)Alds + byte);
            }
            #pragma unroll
            for (int nf = 0; nf < 4; nf++) {
                int n = wn + nf * 16 + lr;
                unsigned byte = n * 128u + ks * 64u + lg * 16u;
                byte ^= ((n & 7u) << 4);
                bf[nf] = *(bf16x8*)((char*)Blds + byte);
            }
            #pragma unroll
            for (int mf = 0; mf < 4; mf++)
                #pragma unroll
                for (int nf = 0; nf < 4; nf++)
                    acc[mf][nf] = __builtin_amdgcn_mfma_f32_16x16x32_bf16(af[mf], bf[nf], acc[mf][nf], 0, 0, 0);
        }
    }

    // epilogue: D row m = wm+mf*16+lg*4+r ; col n = wn+nf*16+lr
    if (MODE == 0 || MODE == 1) {
        unsigned short* ob = outb + (size_t)b * S_ * C_;
        #pragma unroll
        for (int mf = 0; mf < 4; mf++)
            #pragma unroll
            for (int nf = 0; nf < 4; nf++) {
                int cbase = m0 + wm + mf * 16 + lg * 4;
                int srow = n0 + wn + nf * 16 + lr;
                bf16x4 pk;
                #pragma unroll
                for (int r = 0; r < 4; r++) {
                    float v = acc[mf][nf][r] + bias[cbase + r];
                    if (MODE == 0) v *= qscale;
                    pk[r] = (short)f2bf(v);
                }
                *(bf16x4*)(ob + (size_t)srow * C_ + cbase) = pk;
            }
    } else if (MODE == 2) {
        unsigned short* ob = outb + (size_t)b * C_ * S_;
        #pragma unroll
        for (int mf = 0; mf < 4; mf++)
            #pragma unroll
            for (int nf = 0; nf < 4; nf++)
                #pragma unroll
                for (int r = 0; r < 4; r++) {
                    int c = m0 + wm + mf * 16 + lg * 4 + r;
                    int s = n0 + wn + nf * 16 + lr;
                    ob[(size_t)c * S_ + s] = f2bf(acc[mf][nf][r] + bias[c]);
                }
    } else {
        float* ob = outf + (size_t)b * C_ * S_;
        const float* xb = xres + (size_t)b * C_ * S_;
        #pragma unroll
        for (int mf = 0; mf < 4; mf++)
            #pragma unroll
            for (int nf = 0; nf < 4; nf++)
                #pragma unroll
                for (int r = 0; r < 4; r++) {
                    int c = m0 + wm + mf * 16 + lg * 4 + r;
                    int s = n0 + wn + nf * 16 + lr;
                    ob[(size_t)c * S_ + s] = acc[mf][nf][r] + bias[c] + xb[(size_t)c * S_ + s];
                }
    }
}

// ---------------- Flash attention v8: R3 structure + fixed-offset softmax ----------------
// 8 waves x 16q (full 64-key tiles per wave), reg-staged prefetch, 2 barriers/tile.
// Fixed-offset softmax: p = exp2(s - 16); the 2^-16 scale cancels in O = (sum p*v)/(sum p).
// lrun is a per-lane linear accumulator, reduced once at the end (no per-tile shuffles,
// no max tracking, no acc rescale).
__global__ __launch_bounds__(512, 2) void k_attn(const unsigned short* __restrict__ Q,  // [B][S][C], pre-scaled
                                                 const unsigned short* __restrict__ K,  // [B][S][C]
                                                 const unsigned short* __restrict__ V,  // [B][C][S]
                                                 unsigned short* __restrict__ O) {      // [B][S][C]
    // XCD swizzle: all 32 q-blocks of one batch land on one XCD (K/V fit its 4MB L2)
    int b = blockIdx.x & 7;
    int q0 = (blockIdx.x >> 3) * 128;
    int tid = threadIdx.x, lane = tid & 63, wv = tid >> 6;  // 8 waves
    int lr = lane & 15, lg = lane >> 4;
    int qw = q0 + wv * 16;
    __shared__ unsigned short Klds[64 * 256];    // [key][c] rows 512B swz
    __shared__ unsigned short Vlds[256 * 64];    // [c][key] rows 128B swz
    __shared__ unsigned short Plds[8][16 * 64];  // per-wave [q][key] rows 128B swz
    const unsigned short* Qb = Q + (size_t)b * S_ * C_;
    const unsigned short* Kb = K + (size_t)b * S_ * C_;
    const unsigned short* Vb = V + (size_t)b * C_ * S_;

    // Q fragments: q = qw + lr, k-chunk = ks*32 + lg*8
    bf16x8 qf_[8];
    #pragma unroll
    for (int ks = 0; ks < 8; ks++)
        qf_[ks] = *(const bf16x8*)(Qb + (size_t)(qw + lr) * C_ + ks * 32 + lg * 8);

    f32x4 acc[16] = {};  // O^T: c = cf*16+lg*4+r, q = lr
    float lrun = 0.f;    // per-lane partial sum of p (reduced across lg at the end)

    // staging indices (512 threads, 2048 16B-chunks per tile)
    int krow[4], kck[4], vc[4], vck[4];
    #pragma unroll
    for (int i = 0; i < 4; i++) {
        int id = tid + i * 512;
        krow[i] = id >> 5; kck[i] = id & 31;
        vc[i] = id >> 3;  vck[i] = id & 7;
    }

    u32x4 kpre[4], vpre[4];
    // prologue: stage tile 0
    #pragma unroll
    for (int i = 0; i < 4; i++) {
        kpre[i] = *(const u32x4*)(Kb + (size_t)krow[i] * C_ + kck[i] * 8);
        vpre[i] = *(const u32x4*)(Vb + (size_t)vc[i] * S_ + vck[i] * 8);
    }
    #pragma unroll
    for (int i = 0; i < 4; i++) {
        unsigned kb = krow[i] * 512u + kck[i] * 16u; kb ^= ((krow[i] & 7u) << 4);
        *(u32x4*)((char*)Klds + kb) = kpre[i];
        unsigned vb = vc[i] * 128u + vck[i] * 16u; vb ^= ((vc[i] & 7u) << 4);
        *(u32x4*)((char*)Vlds + vb) = vpre[i];
    }
    __syncthreads();

    for (int kt = 0; kt < 64; kt++) {
        // issue next tile's global loads early (latency hidden under MFMA)
        bool pf = (kt + 1) < 64;
        if (pf) {
            #pragma unroll
            for (int i = 0; i < 4; i++) {
                kpre[i] = *(const u32x4*)(Kb + (size_t)((kt + 1) * 64 + krow[i]) * C_ + kck[i] * 8);
                vpre[i] = *(const u32x4*)(Vb + (size_t)vc[i] * S_ + (kt + 1) * 64 + vck[i] * 8);
            }
        }

        // QK^T (swapped): sc holds S[key = kf*16+lg*4+r][q = lr]
        f32x4 sc[4] = {};
        #pragma unroll
        for (int ks = 0; ks < 8; ks++)
            #pragma unroll
            for (int kf = 0; kf < 4; kf++) {
                int key = kf * 16 + lr;
                unsigned byte = key * 512u + ks * 64u + lg * 16u;
                byte ^= ((key & 7u) << 4);
                bf16x8 a = *(bf16x8*)((char*)Klds + byte);
                sc[kf] = __builtin_amdgcn_mfma_f32_16x16x32_bf16(a, qf_[ks], sc[kf], 0, 0, 0);
            }

        // fixed-offset softmax: p = exp2(s - 16); scale cancels at the end
        #pragma unroll
        for (int kf = 0; kf < 4; kf++) {
            bf16x4 pk;
            #pragma unroll
            for (int r = 0; r < 4; r++) {
                float p = __builtin_amdgcn_exp2f(sc[kf][r] - 16.f);
                lrun += p;
                pk[r] = (short)f2bf(p);
            }
            unsigned byte = lr * 128u + (kf * 16u + lg * 4u) * 2u;
            byte ^= ((lr & 7u) << 4);
            *(bf16x4*)((char*)&Plds[wv][0] + byte) = pk;
        }

        // PV: O^T[c][q] += V_cs * P  (wave-private Plds)
        #pragma unroll
        for (int ks2 = 0; ks2 < 2; ks2++) {
            unsigned pbyte = lr * 128u + ks2 * 64u + lg * 16u;
            pbyte ^= ((lr & 7u) << 4);
            bf16x8 pb = *(bf16x8*)((char*)&Plds[wv][0] + pbyte);
            #pragma unroll
            for (int cf = 0; cf < 16; cf++) {
                int c = cf * 16 + lr;
                unsigned byte = c * 128u + ks2 * 64u + lg * 16u;
                byte ^= ((c & 7u) << 4);
                bf16x8 va = *(bf16x8*)((char*)Vlds + byte);
                acc[cf] = __builtin_amdgcn_mfma_f32_16x16x32_bf16(va, pb, acc[cf], 0, 0, 0);
            }
        }

        __syncthreads();  // all waves done reading Klds/Vlds
        if (pf) {
            #pragma unroll
            for (int i = 0; i < 4; i++) {
                unsigned kb = krow[i] * 512u + kck[i] * 16u; kb ^= ((krow[i] & 7u) << 4);
                *(u32x4*)((char*)Klds + kb) = kpre[i];
                unsigned vb = vc[i] * 128u + vck[i] * 16u; vb ^= ((vc[i] & 7u) << 4);
                *(u32x4*)((char*)Vlds + vb) = vpre[i];
            }
        }
        __syncthreads();  // next tile staged
    }

    // reduce l across the 4 lane-groups (each lane summed its lg's keys)
    float lt = lrun;
    lt += __shfl_xor(lt, 16);
    lt += __shfl_xor(lt, 32);

    // normalize + scatter-T store to O[B][S][C]
    unsigned short* Ob = O + (size_t)b * S_ * C_;
    float inv = 1.f / lt;
    int srow = qw + lr;
    #pragma unroll
    for (int cf = 0; cf < 16; cf++) {
        bf16x4 pk;
        #pragma unroll
        for (int r = 0; r < 4; r++) pk[r] = (short)f2bf(acc[cf][r] * inv);
        *(bf16x4*)(Ob + (size_t)srow * C_ + cf * 16 + lg * 4) = pk;
    }
}

__global__ __launch_bounds__(256) void k_copy_temb(const float* __restrict__ t, float* __restrict__ o) {
    int i = blockIdx.x * 256 + threadIdx.x;
    if (i < B_ * 512) o[i] = t[i];
}

extern "C" void kernel_launch(void* const* d_in, const int* in_sizes, int n_in,
                              void* d_out, int out_size, void* d_ws, size_t ws_size,
                              hipStream_t stream) {
    (void)in_sizes; (void)n_in; (void)out_size; (void)ws_size;
    const float* x  = (const float*)d_in[0];
    const float* temb = (const float*)d_in[1];
    const float* gw = (const float*)d_in[2];
    const float* gb = (const float*)d_in[3];
    const float* wq = (const float*)d_in[4];
    const float* bq = (const float*)d_in[5];
    const float* wk = (const float*)d_in[6];
    const float* bk = (const float*)d_in[7];
    const float* wv = (const float*)d_in[8];
    const float* bv = (const float*)d_in[9];
    const float* wp = (const float*)d_in[10];
    const float* bp = (const float*)d_in[11];
    float* out = (float*)d_out;

    char* ws = (char*)d_ws;
    const size_t MB16 = (size_t)B_ * S_ * C_ * 2;           // 16 MB
    unsigned short* h_sc = (unsigned short*)ws;             // [B][S][C]; reused for attn out
    unsigned short* q_sc = (unsigned short*)(ws + MB16);    // [B][S][C]
    unsigned short* k_sc = (unsigned short*)(ws + 2 * MB16);// [B][S][C]
    unsigned short* v_cs = (unsigned short*)(ws + 3 * MB16);// [B][C][S]
    float* stats = (float*)(ws + 4 * MB16);                 // [B*G][2]

    const float qscale = 0.0625f * 1.4426950408889634f;  // C^-0.5 * log2(e)

    k_gn_stats<<<B_ * G_, 256, 0, stream>>>(x, stats);
    k_gn_apply<<<B_ * (S_ / 64), 256, 0, stream>>>(x, stats, gw, gb, h_sc);
    k_gemm<0><<<512, 256, 0, stream>>>(wq, bq, h_sc, q_sc, nullptr, nullptr, qscale);
    k_gemm<1><<<512, 256, 0, stream>>>(wk, bk, h_sc, k_sc, nullptr, nullptr, 1.f);
    k_gemm<2><<<512, 256, 0, stream>>>(wv, bv, h_sc, v_cs, nullptr, nullptr, 1.f);
    k_attn<<<B_ * (S_ / 128), 512, 0, stream>>>(q_sc, k_sc, v_cs, h_sc);
    k_gemm<3><<<512, 256, 0, stream>>>(wp, bp, h_sc, nullptr, out, x, 1.f);
    k_copy_temb<<<(B_ * 512 + 255) / 256, 256, 0, stream>>>(temb, out + (size_t)B_ * C_ * S_);
}